// Round 22
// baseline (75.218 us; speedup 1.0000x reference)
//
#include <hip/hip_runtime.h>

// Problem constants: B=128, n=64, E=65536, K=16, D=64, e_full=524288
#define EF      524288
#define NEDGE   65536
#define KDIM    16
#define DDIM    64
#define TPW     2
#define PVBLK   (EF / (32 * TPW) / 4)   // 2048 blocks, 4 waves each
#define NTILE   (EF / 32)               // 16384 slot-tiles of 32 rows
#define CAP     64                      // edge-list capacity per tile (avg 4)
#define PF      8                       // list entries prefetched per tile

typedef float vfloat4 __attribute__((ext_vector_type(4)));
typedef short bf16x8  __attribute__((ext_vector_type(8)));
typedef float f32x16  __attribute__((ext_vector_type(16)));

__device__ __forceinline__ short f2bf(float f) {   // f32 -> bf16, RNE
    unsigned u = __float_as_uint(f);
    return (short)((u + 0x7FFFu + ((u >> 16) & 1u)) >> 16);
}

__device__ __forceinline__ long edge_slot(const int* ei, int e) {
    int r = ei[e];
    int c = ei[NEDGE + e];
    return ((long)(r >> 6) << 12) + ((long)(r & 63) << 6) + (long)(c & 63);
}

// ws layout: [0,64K) tile counts | [64K,64K+4M) lists | ovf_cnt | ovf list
#define WS_CNT_OFF   0
#define WS_LIST_OFF  (64 * 1024)
#define WS_OVFC_OFF  (WS_LIST_OFF + NTILE * CAP * 4)
#define WS_OVFL_OFF  (WS_OVFC_OFF + 4)
#define WS_NEED      (WS_OVFL_OFF + NEDGE * 4)

// ---------------------------------------------------------------------------
__global__ __launch_bounds__(256) void zero_cnt(unsigned* __restrict__ cnt,
                                                unsigned* __restrict__ ovfc) {
    int gid = blockIdx.x * 256 + threadIdx.x;   // 16384 threads
    cnt[gid] = 0u;
    if (gid == 0) *ovfc = 0u;
}

// ---------------------------------------------------------------------------
__global__ __launch_bounds__(256) void bin_edges(const int* __restrict__ ei,
                                                 unsigned* __restrict__ cnt,
                                                 int* __restrict__ list,
                                                 unsigned* __restrict__ ovfc,
                                                 int* __restrict__ ovfl) {
    int e = blockIdx.x * 256 + threadIdx.x;     // NEDGE threads
    long slot = edge_slot(ei, e);
    int tile = (int)(slot >> 5);
    int row  = (int)(slot & 31);
    unsigned pos = atomicAdd(&cnt[tile], 1u);
    if (pos < CAP) list[tile * CAP + pos] = (e << 5) | row;
    else           ovfl[atomicAdd(ovfc, 1u)] = e;
}

// ---------------------------------------------------------------------------
// pv_fused_reg v2: no LDS; swapped-MFMA layout (lane (n,kh) owns output row n);
// in-register edge adds. FIX vs R21 (rule #20): the edge consume is STATICALLY
// UNROLLED over i in [0,PF) with predication, so pk0/pk1 stay in VGPRs
// (R21's runtime-bound loop demoted them to scratch: VGPR=72, 102us).
// Tail (>PF edges, P~2%) reads list directly (no register-array indexing).
// ---------------------------------------------------------------------------
__global__ __launch_bounds__(256) void pv_fused_reg(const float* __restrict__ pv,
                                                    const float* __restrict__ W,
                                                    const float* __restrict__ ea,
                                                    const unsigned* __restrict__ cnt,
                                                    const int* __restrict__ list,
                                                    float* __restrict__ out,
                                                    float* __restrict__ outv) {
    int tid = threadIdx.x;
    int wv  = tid >> 6;
    int l   = tid & 63;
    int n   = l & 31;
    int kh  = l >> 5;
    long j0 = ((long)blockIdx.x * 4 + wv) * (32 * TPW);
    int tile0 = (int)(j0 >> 5);

    // ---- prologue: independent loads ----
    unsigned ec0 = cnt[tile0];
    unsigned ec1 = cnt[tile0 + 1];
    int pk0[PF], pk1[PF];
#pragma unroll
    for (int i = 0; i < PF; ++i) {
        pk0[i] = list[(long)tile0 * CAP + i];
        pk1[i] = list[(long)(tile0 + 1) * CAP + i];
    }

    // idx fill for this block's 256 rows (independent; hides latency)
    {
        int j = blockIdx.x * 256 + tid;         // [0, EF)
        int g = j >> 12;
        int rem = j & 4095;
        out[j]      = (float)((g << 6) + (rem >> 6));
        out[EF + j] = (float)((g << 6) + (rem & 63));
    }

    // pv fragments (both tiles)
    const float4* bp0 = reinterpret_cast<const float4*>(pv + (j0 + n) * KDIM + kh * 8);
    const float4* bp1 = reinterpret_cast<const float4*>(pv + (j0 + 32 + n) * KDIM + kh * 8);
    float4 ba0 = bp0[0], bb0 = bp0[1], ba1 = bp1[0], bb1 = bp1[1];

    // W fragments (L1-resident)
    const float4* wp0 = reinterpret_cast<const float4*>(W + n * KDIM + kh * 8);
    const float4* wp1 = reinterpret_cast<const float4*>(W + (32 + n) * KDIM + kh * 8);
    float4 w0a = wp0[0], w0b = wp0[1], w1a = wp1[0], w1b = wp1[1];
    bf16x8 xa0, xa1;
    xa0[0]=f2bf(w0a.x); xa0[1]=f2bf(w0a.y); xa0[2]=f2bf(w0a.z); xa0[3]=f2bf(w0a.w);
    xa0[4]=f2bf(w0b.x); xa0[5]=f2bf(w0b.y); xa0[6]=f2bf(w0b.z); xa0[7]=f2bf(w0b.w);
    xa1[0]=f2bf(w1a.x); xa1[1]=f2bf(w1a.y); xa1[2]=f2bf(w1a.z); xa1[3]=f2bf(w1a.w);
    xa1[4]=f2bf(w1b.x); xa1[5]=f2bf(w1b.y); xa1[6]=f2bf(w1b.z); xa1[7]=f2bf(w1b.w);

    unsigned ecc0 = ec0 > CAP ? CAP : ec0;
    unsigned ecc1 = ec1 > CAP ? CAP : ec1;

#pragma unroll
    for (int tt = 0; tt < TPW; ++tt) {          // tt compile-time after unroll
        long jt = j0 + tt * 32;
        float4 ba = tt ? ba1 : ba0;
        float4 bb = tt ? bb1 : bb0;
        unsigned ec = tt ? ecc1 : ecc0;
        int tile = tile0 + tt;

        bf16x8 yf;
        yf[0]=f2bf(ba.x); yf[1]=f2bf(ba.y); yf[2]=f2bf(ba.z); yf[3]=f2bf(ba.w);
        yf[4]=f2bf(bb.x); yf[5]=f2bf(bb.y); yf[6]=f2bf(bb.z); yf[7]=f2bf(bb.w);

        f32x16 acc0 = {0,0,0,0, 0,0,0,0, 0,0,0,0, 0,0,0,0};
        f32x16 acc1 = {0,0,0,0, 0,0,0,0, 0,0,0,0, 0,0,0,0};
        acc0 = __builtin_amdgcn_mfma_f32_32x32x16_bf16(xa0, yf, acc0, 0, 0, 0);
        acc1 = __builtin_amdgcn_mfma_f32_32x32x16_bf16(xa1, yf, acc1, 0, 0, 0);

        // ---- in-register edge adds: STATIC unroll, compile-time indices ----
#pragma unroll
        for (int i = 0; i < PF; ++i) {
            int packed = tt ? pk1[i] : pk0[i];          // static index -> VGPR
            if ((unsigned)i < ec && n == (packed & 31)) {
                long eb = (long)(packed >> 5) * DDIM;
                const float4* er = reinterpret_cast<const float4*>(ea + eb + kh * 4);
#pragma unroll
                for (int q = 0; q < 4; ++q) {
                    float4 e0 = er[2*q];        // cols 8q+4kh..+3
                    float4 e1 = er[2*q + 8];    // cols 32+8q+4kh..+3
                    acc0[4*q]   += e0.x; acc0[4*q+1] += e0.y;
                    acc0[4*q+2] += e0.z; acc0[4*q+3] += e0.w;
                    acc1[4*q]   += e1.x; acc1[4*q+1] += e1.y;
                    acc1[4*q+2] += e1.z; acc1[4*q+3] += e1.w;
                }
            }
        }
        // tail (>PF edges in a tile: rare) -- reads list directly
        for (unsigned i = PF; i < ec; ++i) {
            int packed = list[(long)tile * CAP + i];
            if (n == (packed & 31)) {
                long eb = (long)(packed >> 5) * DDIM;
                const float4* er = reinterpret_cast<const float4*>(ea + eb + kh * 4);
#pragma unroll
                for (int q = 0; q < 4; ++q) {
                    float4 e0 = er[2*q];
                    float4 e1 = er[2*q + 8];
                    acc0[4*q]   += e0.x; acc0[4*q+1] += e0.y;
                    acc0[4*q+2] += e0.z; acc0[4*q+3] += e0.w;
                    acc1[4*q]   += e1.x; acc1[4*q+1] += e1.y;
                    acc1[4*q+2] += e1.z; acc1[4*q+3] += e1.w;
                }
            }
        }

        // ---- direct float4 stores (R14-probe-proven ~roofline) ----
        float* base = outv + (jt + n) * DDIM + kh * 4;
#pragma unroll
        for (int q = 0; q < 4; ++q) {
            vfloat4 s0 = {acc0[4*q], acc0[4*q+1], acc0[4*q+2], acc0[4*q+3]};
            vfloat4 s1 = {acc1[4*q], acc1[4*q+1], acc1[4*q+2], acc1[4*q+3]};
            *reinterpret_cast<vfloat4*>(base + 8*q)      = s0;
            *reinterpret_cast<vfloat4*>(base + 8*q + 32) = s1;
        }
    }
}

// ---------------------------------------------------------------------------
__global__ __launch_bounds__(256) void ovf_fix(const float* __restrict__ ea,
                                               const int* __restrict__ ei,
                                               const unsigned* __restrict__ ovfc,
                                               const int* __restrict__ ovfl,
                                               float* __restrict__ outv) {
    unsigned nov = *ovfc;
    for (unsigned i = blockIdx.x * 256 + threadIdx.x; i < nov; i += 4 * 256) {
        int e = ovfl[i];
        long slot = edge_slot(ei, e);
        float* dst = outv + slot * DDIM;
        const float* src = ea + (long)e * DDIM;
        for (int j = 0; j < DDIM; ++j) unsafeAtomicAdd(dst + j, src[j]);
    }
}

// ---------------------------------------------------------------------------
// Fallback: proven separate path when ws too small.
// ---------------------------------------------------------------------------
__global__ __launch_bounds__(256) void pv_gemm(const float* __restrict__ pv,
                                               const float* __restrict__ W,
                                               float* __restrict__ outv) {
    int tid = threadIdx.x;
    int wv  = tid >> 6;
    int l   = tid & 63;
    int n   = l & 31;
    int kh  = l >> 5;
    long j0 = ((long)blockIdx.x * 4 + wv) * 64;

    const float4* wp0 = reinterpret_cast<const float4*>(W + n * KDIM + kh * 8);
    const float4* wp1 = reinterpret_cast<const float4*>(W + (32 + n) * KDIM + kh * 8);
    float4 w0a = wp0[0], w0b = wp0[1], w1a = wp1[0], w1b = wp1[1];
    bf16x8 xa0, xa1;
    xa0[0]=f2bf(w0a.x); xa0[1]=f2bf(w0a.y); xa0[2]=f2bf(w0a.z); xa0[3]=f2bf(w0a.w);
    xa0[4]=f2bf(w0b.x); xa0[5]=f2bf(w0b.y); xa0[6]=f2bf(w0b.z); xa0[7]=f2bf(w0b.w);
    xa1[0]=f2bf(w1a.x); xa1[1]=f2bf(w1a.y); xa1[2]=f2bf(w1a.z); xa1[3]=f2bf(w1a.w);
    xa1[4]=f2bf(w1b.x); xa1[5]=f2bf(w1b.y); xa1[6]=f2bf(w1b.z); xa1[7]=f2bf(w1b.w);

#pragma unroll
    for (int t = 0; t < 2; ++t) {
        long jt = j0 + t * 32;
        const float4* bp = reinterpret_cast<const float4*>(pv + (jt + n) * KDIM + kh * 8);
        float4 ba = bp[0], bb = bp[1];
        bf16x8 yf;
        yf[0]=f2bf(ba.x); yf[1]=f2bf(ba.y); yf[2]=f2bf(ba.z); yf[3]=f2bf(ba.w);
        yf[4]=f2bf(bb.x); yf[5]=f2bf(bb.y); yf[6]=f2bf(bb.z); yf[7]=f2bf(bb.w);

        f32x16 acc0 = {0,0,0,0, 0,0,0,0, 0,0,0,0, 0,0,0,0};
        f32x16 acc1 = {0,0,0,0, 0,0,0,0, 0,0,0,0, 0,0,0,0};
        acc0 = __builtin_amdgcn_mfma_f32_32x32x16_bf16(xa0, yf, acc0, 0, 0, 0);
        acc1 = __builtin_amdgcn_mfma_f32_32x32x16_bf16(xa1, yf, acc1, 0, 0, 0);

        float* base = outv + (jt + n) * DDIM + kh * 4;
#pragma unroll
        for (int q = 0; q < 4; ++q) {
            vfloat4 s0 = {acc0[4*q], acc0[4*q+1], acc0[4*q+2], acc0[4*q+3]};
            vfloat4 s1 = {acc1[4*q], acc1[4*q+1], acc1[4*q+2], acc1[4*q+3]};
            *reinterpret_cast<vfloat4*>(base + 8*q)      = s0;
            *reinterpret_cast<vfloat4*>(base + 8*q + 32) = s1;
        }
    }
}

__global__ __launch_bounds__(256) void fill_idx_plain(float* __restrict__ out) {
    int gid = blockIdx.x * 256 + threadIdx.x;
    int j0 = gid << 2;
    vfloat4 rv, cv;
#pragma unroll
    for (int i = 0; i < 4; ++i) {
        int j = j0 + i;
        int g = j >> 12;
        int rem = j & 4095;
        rv[i] = (float)((g << 6) + (rem >> 6));
        cv[i] = (float)((g << 6) + (rem & 63));
    }
    *reinterpret_cast<vfloat4*>(out + j0)      = rv;
    *reinterpret_cast<vfloat4*>(out + EF + j0) = cv;
}

__global__ __launch_bounds__(256) void scatter_edges(const float* __restrict__ ea,
                                                     const int* __restrict__ ei,
                                                     float* __restrict__ outv) {
    int gid = blockIdx.x * 256 + threadIdx.x;
    int e = gid >> 4;
    int t = gid & 15;
    long slot = edge_slot(ei, e);
    float4 v = *reinterpret_cast<const float4*>(ea + (long)e * DDIM + t * 4);
    float* dst = outv + slot * DDIM + t * 4;
    unsafeAtomicAdd(dst + 0, v.x);
    unsafeAtomicAdd(dst + 1, v.y);
    unsafeAtomicAdd(dst + 2, v.z);
    unsafeAtomicAdd(dst + 3, v.w);
}

extern "C" void kernel_launch(void* const* d_in, const int* in_sizes, int n_in,
                              void* d_out, int out_size, void* d_ws, size_t ws_size,
                              hipStream_t stream) {
    const float* poly_val  = (const float*)d_in[0];
    const float* edge_attr = (const float*)d_in[1];
    const float* W         = (const float*)d_in[2];
    const int*   edge_index = (const int*)d_in[4];

    float* out  = (float*)d_out;
    float* outv = out + 2 * (long)EF;

    if (ws_size >= (size_t)WS_NEED) {
        char* ws = (char*)d_ws;
        unsigned* cnt  = (unsigned*)(ws + WS_CNT_OFF);
        int*      list = (int*)     (ws + WS_LIST_OFF);
        unsigned* ovfc = (unsigned*)(ws + WS_OVFC_OFF);
        int*      ovfl = (int*)     (ws + WS_OVFL_OFF);

        zero_cnt<<<NTILE / 256, 256, 0, stream>>>(cnt, ovfc);
        bin_edges<<<NEDGE / 256, 256, 0, stream>>>(edge_index, cnt, list, ovfc, ovfl);
        pv_fused_reg<<<PVBLK, 256, 0, stream>>>(poly_val, W, edge_attr, cnt, list, out, outv);
        ovf_fix<<<4, 256, 0, stream>>>(edge_attr, edge_index, ovfc, ovfl, outv);
    } else {
        fill_idx_plain<<<EF / 4 / 256, 256, 0, stream>>>(out);
        pv_gemm<<<EF / 256, 256, 0, stream>>>(poly_val, W, outv);
        scatter_edges<<<(NEDGE * 16) / 256, 256, 0, stream>>>(edge_attr, edge_index, outv);
    }
}

// Round 23
// 72.383 us; speedup vs baseline: 1.0392x; 1.0392x over previous
//
#include <hip/hip_runtime.h>

// Problem constants: B=128, n=64, E=65536, K=16, D=64, e_full=524288
#define EF      524288
#define NEDGE   65536
#define KDIM    16
#define DDIM    64
#define TPW     2
#define PVBLK   (EF / (32 * TPW) / 4)   // 2048 blocks, 4 waves each

typedef float vfloat4 __attribute__((ext_vector_type(4)));
typedef short bf16x8  __attribute__((ext_vector_type(8)));
typedef float f32x16  __attribute__((ext_vector_type(16)));

__device__ __forceinline__ short f2bf(float f) {   // f32 -> bf16, RNE
    unsigned u = __float_as_uint(f);
    return (short)((u + 0x7FFFu + ((u >> 16) & 1u)) >> 16);
}

__device__ __forceinline__ long edge_slot(const int* ei, int e) {
    int r = ei[e];
    int c = ei[NEDGE + e];
    return ((long)(r >> 6) << 12) + ((long)(r & 63) << 6) + (long)(c & 63);
}

// ws layout (per-ROW edge lists; slot IS the output row index):
//   cnt  : uint[EF]        @ 0        (2 MB)  -- edges landing on each row
//   lst  : uint[EF]        @ 2 MB     (2 MB)  -- 2 packed u16 edge ids/row
//   ovfc : uint             @ 4 MB
//   ovfl : int[NEDGE]       @ 4 MB+4  (256 KB)
#define WS_CNT_OFF   0
#define WS_LST_OFF   (EF * 4)
#define WS_OVFC_OFF  (WS_LST_OFF + EF * 4)
#define WS_OVFL_OFF  (WS_OVFC_OFF + 4)
#define WS_NEED      (WS_OVFL_OFF + NEDGE * 4)

// ---------------------------------------------------------------------------
__global__ __launch_bounds__(256) void zero_cnt(unsigned* __restrict__ cnt,
                                                unsigned* __restrict__ ovfc) {
    int gid = blockIdx.x * 256 + threadIdx.x;   // EF/4 threads
    reinterpret_cast<uint4*>(cnt)[gid] = make_uint4(0, 0, 0, 0);
    if (gid == 0) *ovfc = 0u;
}

// ---------------------------------------------------------------------------
// bin_edges: per-ROW list. pos<2 -> packed u16 slot in lst; else overflow.
// ---------------------------------------------------------------------------
__global__ __launch_bounds__(256) void bin_edges(const int* __restrict__ ei,
                                                 unsigned* __restrict__ cnt,
                                                 unsigned short* __restrict__ lst16,
                                                 unsigned* __restrict__ ovfc,
                                                 int* __restrict__ ovfl) {
    int e = blockIdx.x * 256 + threadIdx.x;     // NEDGE threads
    long row = edge_slot(ei, e);                // row index in [0, EF)
    unsigned pos = atomicAdd(&cnt[row], 1u);
    if (pos < 2u) lst16[row * 2 + pos] = (unsigned short)e;
    else          ovfl[atomicAdd(ovfc, 1u)] = e;
}

// ---------------------------------------------------------------------------
// pv_fused_reg v3: no LDS, swapped-MFMA layout (lane (n,kh) owns row jt+n),
// BRANCH-FREE per-lane edge adds. Each lane reads its own row's cnt + packed
// u16 edge pair, loads BOTH candidate ea rows unconditionally (garbage u16
// ids are always in-bounds; junk values killed by fma with valid in {0,1}).
// Single basic block -> all loads issue together, hidden under MFMA+stores.
// (R21/R22 failed because divergent branch bodies serialized the ea loads.)
// ---------------------------------------------------------------------------
__global__ __launch_bounds__(256) void pv_fused_reg(const float* __restrict__ pv,
                                                    const float* __restrict__ W,
                                                    const float* __restrict__ ea,
                                                    const unsigned* __restrict__ cnt,
                                                    const unsigned* __restrict__ lst,
                                                    float* __restrict__ out,
                                                    float* __restrict__ outv) {
    int tid = threadIdx.x;
    int wv  = tid >> 6;
    int l   = tid & 63;
    int n   = l & 31;
    int kh  = l >> 5;
    long j0 = ((long)blockIdx.x * 4 + wv) * (32 * TPW);
    long jA = j0 + n;            // this lane's row in tile 0
    long jB = j0 + 32 + n;       // this lane's row in tile 1

    // ---- prologue: per-lane row metadata (coalesced) ----
    unsigned rcA = cnt[jA], rcB = cnt[jB];
    unsigned leA = lst[jA],  leB = lst[jB];     // 2 packed u16 edge ids

    // idx fill for this block's 256 rows (independent; hides latency)
    {
        int j = blockIdx.x * 256 + tid;         // [0, EF)
        int g = j >> 12;
        int rem = j & 4095;
        out[j]      = (float)((g << 6) + (rem >> 6));
        out[EF + j] = (float)((g << 6) + (rem & 63));
    }

    // ---- edge row pointers (unconditional; u16 ids always in-bounds) ----
    const float* pA0 = ea + (long)(leA & 0xFFFFu) * DDIM + kh * 4;
    const float* pA1 = ea + (long)(leA >> 16)     * DDIM + kh * 4;
    const float* pB0 = ea + (long)(leB & 0xFFFFu) * DDIM + kh * 4;
    const float* pB1 = ea + (long)(leB >> 16)     * DDIM + kh * 4;
    float vA0 = rcA >= 1u ? 1.f : 0.f, vA1 = rcA >= 2u ? 1.f : 0.f;
    float vB0 = rcB >= 1u ? 1.f : 0.f, vB1 = rcB >= 2u ? 1.f : 0.f;

    // ---- pv fragments (both tiles) ----
    const float4* bp0 = reinterpret_cast<const float4*>(pv + jA * KDIM + kh * 8);
    const float4* bp1 = reinterpret_cast<const float4*>(pv + jB * KDIM + kh * 8);
    float4 ba0 = bp0[0], bb0 = bp0[1], ba1 = bp1[0], bb1 = bp1[1];

    // ---- W fragments (L1-resident) ----
    const float4* wp0 = reinterpret_cast<const float4*>(W + n * KDIM + kh * 8);
    const float4* wp1 = reinterpret_cast<const float4*>(W + (32 + n) * KDIM + kh * 8);
    float4 w0a = wp0[0], w0b = wp0[1], w1a = wp1[0], w1b = wp1[1];
    bf16x8 xa0, xa1;
    xa0[0]=f2bf(w0a.x); xa0[1]=f2bf(w0a.y); xa0[2]=f2bf(w0a.z); xa0[3]=f2bf(w0a.w);
    xa0[4]=f2bf(w0b.x); xa0[5]=f2bf(w0b.y); xa0[6]=f2bf(w0b.z); xa0[7]=f2bf(w0b.w);
    xa1[0]=f2bf(w1a.x); xa1[1]=f2bf(w1a.y); xa1[2]=f2bf(w1a.z); xa1[3]=f2bf(w1a.w);
    xa1[4]=f2bf(w1b.x); xa1[5]=f2bf(w1b.y); xa1[6]=f2bf(w1b.z); xa1[7]=f2bf(w1b.w);

    // ================= tile 0 =================
    {
        bf16x8 yf;
        yf[0]=f2bf(ba0.x); yf[1]=f2bf(ba0.y); yf[2]=f2bf(ba0.z); yf[3]=f2bf(ba0.w);
        yf[4]=f2bf(bb0.x); yf[5]=f2bf(bb0.y); yf[6]=f2bf(bb0.z); yf[7]=f2bf(bb0.w);
        f32x16 acc0 = {0,0,0,0, 0,0,0,0, 0,0,0,0, 0,0,0,0};
        f32x16 acc1 = {0,0,0,0, 0,0,0,0, 0,0,0,0, 0,0,0,0};
        acc0 = __builtin_amdgcn_mfma_f32_32x32x16_bf16(xa0, yf, acc0, 0, 0, 0);
        acc1 = __builtin_amdgcn_mfma_f32_32x32x16_bf16(xa1, yf, acc1, 0, 0, 0);

        // branch-free edge adds (fma-predicated)
#pragma unroll
        for (int q = 0; q < 4; ++q) {
            float4 a0 = reinterpret_cast<const float4*>(pA0)[2*q];
            float4 a1 = reinterpret_cast<const float4*>(pA0)[2*q + 8];
            float4 b0 = reinterpret_cast<const float4*>(pA1)[2*q];
            float4 b1 = reinterpret_cast<const float4*>(pA1)[2*q + 8];
            acc0[4*q]   += vA0*a0.x + vA1*b0.x;
            acc0[4*q+1] += vA0*a0.y + vA1*b0.y;
            acc0[4*q+2] += vA0*a0.z + vA1*b0.z;
            acc0[4*q+3] += vA0*a0.w + vA1*b0.w;
            acc1[4*q]   += vA0*a1.x + vA1*b1.x;
            acc1[4*q+1] += vA0*a1.y + vA1*b1.y;
            acc1[4*q+2] += vA0*a1.z + vA1*b1.z;
            acc1[4*q+3] += vA0*a1.w + vA1*b1.w;
        }

        float* base = outv + jA * DDIM + kh * 4;
#pragma unroll
        for (int q = 0; q < 4; ++q) {
            vfloat4 s0 = {acc0[4*q], acc0[4*q+1], acc0[4*q+2], acc0[4*q+3]};
            vfloat4 s1 = {acc1[4*q], acc1[4*q+1], acc1[4*q+2], acc1[4*q+3]};
            *reinterpret_cast<vfloat4*>(base + 8*q)      = s0;
            *reinterpret_cast<vfloat4*>(base + 8*q + 32) = s1;
        }
    }

    // ================= tile 1 =================
    {
        bf16x8 yf;
        yf[0]=f2bf(ba1.x); yf[1]=f2bf(ba1.y); yf[2]=f2bf(ba1.z); yf[3]=f2bf(ba1.w);
        yf[4]=f2bf(bb1.x); yf[5]=f2bf(bb1.y); yf[6]=f2bf(bb1.z); yf[7]=f2bf(bb1.w);
        f32x16 acc0 = {0,0,0,0, 0,0,0,0, 0,0,0,0, 0,0,0,0};
        f32x16 acc1 = {0,0,0,0, 0,0,0,0, 0,0,0,0, 0,0,0,0};
        acc0 = __builtin_amdgcn_mfma_f32_32x32x16_bf16(xa0, yf, acc0, 0, 0, 0);
        acc1 = __builtin_amdgcn_mfma_f32_32x32x16_bf16(xa1, yf, acc1, 0, 0, 0);

#pragma unroll
        for (int q = 0; q < 4; ++q) {
            float4 a0 = reinterpret_cast<const float4*>(pB0)[2*q];
            float4 a1 = reinterpret_cast<const float4*>(pB0)[2*q + 8];
            float4 b0 = reinterpret_cast<const float4*>(pB1)[2*q];
            float4 b1 = reinterpret_cast<const float4*>(pB1)[2*q + 8];
            acc0[4*q]   += vB0*a0.x + vB1*b0.x;
            acc0[4*q+1] += vB0*a0.y + vB1*b0.y;
            acc0[4*q+2] += vB0*a0.z + vB1*b0.z;
            acc0[4*q+3] += vB0*a0.w + vB1*b0.w;
            acc1[4*q]   += vB0*a1.x + vB1*b1.x;
            acc1[4*q+1] += vB0*a1.y + vB1*b1.y;
            acc1[4*q+2] += vB0*a1.z + vB1*b1.z;
            acc1[4*q+3] += vB0*a1.w + vB1*b1.w;
        }

        float* base = outv + jB * DDIM + kh * 4;
#pragma unroll
        for (int q = 0; q < 4; ++q) {
            vfloat4 s0 = {acc0[4*q], acc0[4*q+1], acc0[4*q+2], acc0[4*q+3]};
            vfloat4 s1 = {acc1[4*q], acc1[4*q+1], acc1[4*q+2], acc1[4*q+3]};
            *reinterpret_cast<vfloat4*>(base + 8*q)      = s0;
            *reinterpret_cast<vfloat4*>(base + 8*q + 32) = s1;
        }
    }
}

// ---------------------------------------------------------------------------
// ovf_fix: rows with >2 edges (expected ~160 edges chip-wide).
// ---------------------------------------------------------------------------
__global__ __launch_bounds__(256) void ovf_fix(const float* __restrict__ ea,
                                               const int* __restrict__ ei,
                                               const unsigned* __restrict__ ovfc,
                                               const int* __restrict__ ovfl,
                                               float* __restrict__ outv) {
    unsigned nov = *ovfc;
    for (unsigned i = blockIdx.x * 256 + threadIdx.x; i < nov; i += 8 * 256) {
        int e = ovfl[i];
        long slot = edge_slot(ei, e);
        float* dst = outv + slot * DDIM;
        const float* src = ea + (long)e * DDIM;
        for (int j = 0; j < DDIM; ++j) unsafeAtomicAdd(dst + j, src[j]);
    }
}

// ---------------------------------------------------------------------------
// Fallback: proven separate path when ws too small.
// ---------------------------------------------------------------------------
__global__ __launch_bounds__(256) void pv_gemm(const float* __restrict__ pv,
                                               const float* __restrict__ W,
                                               float* __restrict__ outv) {
    int tid = threadIdx.x;
    int wv  = tid >> 6;
    int l   = tid & 63;
    int n   = l & 31;
    int kh  = l >> 5;
    long j0 = ((long)blockIdx.x * 4 + wv) * 64;

    const float4* wp0 = reinterpret_cast<const float4*>(W + n * KDIM + kh * 8);
    const float4* wp1 = reinterpret_cast<const float4*>(W + (32 + n) * KDIM + kh * 8);
    float4 w0a = wp0[0], w0b = wp0[1], w1a = wp1[0], w1b = wp1[1];
    bf16x8 xa0, xa1;
    xa0[0]=f2bf(w0a.x); xa0[1]=f2bf(w0a.y); xa0[2]=f2bf(w0a.z); xa0[3]=f2bf(w0a.w);
    xa0[4]=f2bf(w0b.x); xa0[5]=f2bf(w0b.y); xa0[6]=f2bf(w0b.z); xa0[7]=f2bf(w0b.w);
    xa1[0]=f2bf(w1a.x); xa1[1]=f2bf(w1a.y); xa1[2]=f2bf(w1a.z); xa1[3]=f2bf(w1a.w);
    xa1[4]=f2bf(w1b.x); xa1[5]=f2bf(w1b.y); xa1[6]=f2bf(w1b.z); xa1[7]=f2bf(w1b.w);

#pragma unroll
    for (int t = 0; t < 2; ++t) {
        long jt = j0 + t * 32;
        const float4* bp = reinterpret_cast<const float4*>(pv + (jt + n) * KDIM + kh * 8);
        float4 ba = bp[0], bb = bp[1];
        bf16x8 yf;
        yf[0]=f2bf(ba.x); yf[1]=f2bf(ba.y); yf[2]=f2bf(ba.z); yf[3]=f2bf(ba.w);
        yf[4]=f2bf(bb.x); yf[5]=f2bf(bb.y); yf[6]=f2bf(bb.z); yf[7]=f2bf(bb.w);

        f32x16 acc0 = {0,0,0,0, 0,0,0,0, 0,0,0,0, 0,0,0,0};
        f32x16 acc1 = {0,0,0,0, 0,0,0,0, 0,0,0,0, 0,0,0,0};
        acc0 = __builtin_amdgcn_mfma_f32_32x32x16_bf16(xa0, yf, acc0, 0, 0, 0);
        acc1 = __builtin_amdgcn_mfma_f32_32x32x16_bf16(xa1, yf, acc1, 0, 0, 0);

        float* base = outv + (jt + n) * DDIM + kh * 4;
#pragma unroll
        for (int q = 0; q < 4; ++q) {
            vfloat4 s0 = {acc0[4*q], acc0[4*q+1], acc0[4*q+2], acc0[4*q+3]};
            vfloat4 s1 = {acc1[4*q], acc1[4*q+1], acc1[4*q+2], acc1[4*q+3]};
            *reinterpret_cast<vfloat4*>(base + 8*q)      = s0;
            *reinterpret_cast<vfloat4*>(base + 8*q + 32) = s1;
        }
    }
}

__global__ __launch_bounds__(256) void fill_idx_plain(float* __restrict__ out) {
    int gid = blockIdx.x * 256 + threadIdx.x;
    int j0 = gid << 2;
    vfloat4 rv, cv;
#pragma unroll
    for (int i = 0; i < 4; ++i) {
        int j = j0 + i;
        int g = j >> 12;
        int rem = j & 4095;
        rv[i] = (float)((g << 6) + (rem >> 6));
        cv[i] = (float)((g << 6) + (rem & 63));
    }
    *reinterpret_cast<vfloat4*>(out + j0)      = rv;
    *reinterpret_cast<vfloat4*>(out + EF + j0) = cv;
}

__global__ __launch_bounds__(256) void scatter_edges(const float* __restrict__ ea,
                                                     const int* __restrict__ ei,
                                                     float* __restrict__ outv) {
    int gid = blockIdx.x * 256 + threadIdx.x;
    int e = gid >> 4;
    int t = gid & 15;
    long slot = edge_slot(ei, e);
    float4 v = *reinterpret_cast<const float4*>(ea + (long)e * DDIM + t * 4);
    float* dst = outv + slot * DDIM + t * 4;
    unsafeAtomicAdd(dst + 0, v.x);
    unsafeAtomicAdd(dst + 1, v.y);
    unsafeAtomicAdd(dst + 2, v.z);
    unsafeAtomicAdd(dst + 3, v.w);
}

extern "C" void kernel_launch(void* const* d_in, const int* in_sizes, int n_in,
                              void* d_out, int out_size, void* d_ws, size_t ws_size,
                              hipStream_t stream) {
    const float* poly_val  = (const float*)d_in[0];
    const float* edge_attr = (const float*)d_in[1];
    const float* W         = (const float*)d_in[2];
    const int*   edge_index = (const int*)d_in[4];

    float* out  = (float*)d_out;
    float* outv = out + 2 * (long)EF;

    if (ws_size >= (size_t)WS_NEED) {
        char* ws = (char*)d_ws;
        unsigned*       cnt   = (unsigned*)(ws + WS_CNT_OFF);
        unsigned*       lst   = (unsigned*)(ws + WS_LST_OFF);
        unsigned short* lst16 = (unsigned short*)(ws + WS_LST_OFF);
        unsigned*       ovfc  = (unsigned*)(ws + WS_OVFC_OFF);
        int*            ovfl  = (int*)     (ws + WS_OVFL_OFF);

        zero_cnt<<<EF / 4 / 256, 256, 0, stream>>>(cnt, ovfc);
        bin_edges<<<NEDGE / 256, 256, 0, stream>>>(edge_index, cnt, lst16, ovfc, ovfl);
        pv_fused_reg<<<PVBLK, 256, 0, stream>>>(poly_val, W, edge_attr, cnt, lst, out, outv);
        ovf_fix<<<8, 256, 0, stream>>>(edge_attr, edge_index, ovfc, ovfl, outv);
    } else {
        fill_idx_plain<<<EF / 4 / 256, 256, 0, stream>>>(out);
        pv_gemm<<<EF / 256, 256, 0, stream>>>(poly_val, W, outv);
        scatter_edges<<<(NEDGE * 16) / 256, 256, 0, stream>>>(edge_attr, edge_index, outv);
    }
}

// Round 24
// 45.137 us; speedup vs baseline: 1.6664x; 1.6036x over previous
//
#include <hip/hip_runtime.h>

// Problem constants: B=128, n=64, E=65536, K=16, D=64, e_full=524288
#define EF      524288
#define NEDGE   65536
#define KDIM    16
#define DDIM    64
#define TPW     2
#define PVBLK   (EF / (32 * TPW) / 4)   // 2048 blocks, 4 waves each
#define LSTR    68
#define NTILE   (EF / 32)               // 16384 slot-tiles of 32 rows
#define CAP     64                      // edge-list capacity per tile (avg 4)
#define PF      8                       // edge rows prefetched per tile

typedef float vfloat4 __attribute__((ext_vector_type(4)));
typedef short bf16x8  __attribute__((ext_vector_type(8)));
typedef float f32x16  __attribute__((ext_vector_type(16)));

__device__ __forceinline__ short f2bf(float f) {   // f32 -> bf16, RNE
    unsigned u = __float_as_uint(f);
    return (short)((u + 0x7FFFu + ((u >> 16) & 1u)) >> 16);
}

__device__ __forceinline__ long edge_slot(const int* ei, int e) {
    int r = ei[e];
    int c = ei[NEDGE + e];
    return ((long)(r >> 6) << 12) + ((long)(r & 63) << 6) + (long)(c & 63);
}

// ws layout: [0,64K) tile counts | [64K,64K+4M) lists | ovf_cnt | ovf list
#define WS_CNT_OFF   0
#define WS_LIST_OFF  (64 * 1024)
#define WS_OVFC_OFF  (WS_LIST_OFF + NTILE * CAP * 4)
#define WS_OVFL_OFF  (WS_OVFC_OFF + 4)
#define WS_NEED      (WS_OVFL_OFF + NEDGE * 4)

// ---------------------------------------------------------------------------
__global__ __launch_bounds__(256) void zero_cnt(unsigned* __restrict__ cnt,
                                                unsigned* __restrict__ ovfc) {
    int gid = blockIdx.x * 256 + threadIdx.x;   // 16384 threads
    cnt[gid] = 0u;
    if (gid == 0) *ovfc = 0u;
}

// ---------------------------------------------------------------------------
__global__ __launch_bounds__(256) void bin_edges(const int* __restrict__ ei,
                                                 unsigned* __restrict__ cnt,
                                                 int* __restrict__ list,
                                                 unsigned* __restrict__ ovfc,
                                                 int* __restrict__ ovfl) {
    int e = blockIdx.x * 256 + threadIdx.x;     // NEDGE threads
    long slot = edge_slot(ei, e);
    int tile = (int)(slot >> 5);
    int row  = (int)(slot & 31);
    unsigned pos = atomicAdd(&cnt[tile], 1u);
    if (pos < CAP) list[tile * CAP + pos] = (e << 5) | row;
    else           ovfl[atomicAdd(ovfc, 1u)] = e;
}

// ---------------------------------------------------------------------------
// pv_fused v5 (session best, 45.18us):
//  * ea prefetch UNCONDITIONAL with clamped edge index ((u>>5)&65535) --
//    breaks the cnt->ea dependence; prologue = cnt || (list->ea) || pv || W.
//    Garbage entries past ec load in-bounds junk that is never consumed.
//  * idx-fill folded in: each block writes its 256 contiguous out floats
//    in the latency shadow between load-issue and MFMA.
//  * per-wave LDS tile for the coalesced binned edge adds; dense 1KB stores.
// ---------------------------------------------------------------------------
__global__ __launch_bounds__(256) void pv_fused(const float* __restrict__ pv,
                                                const float* __restrict__ W,
                                                const float* __restrict__ ea,
                                                const unsigned* __restrict__ cnt,
                                                const int* __restrict__ list,
                                                float* __restrict__ out,
                                                float* __restrict__ outv) {
    __shared__ float lds[4][32 * LSTR];
    int tid = threadIdx.x;
    int wv  = tid >> 6;
    int l   = tid & 63;
    int n   = l & 31;
    int kh  = l >> 5;
    long j0 = ((long)blockIdx.x * 4 + wv) * (32 * TPW);
    int tile0 = (int)(j0 >> 5);

    // ---- issue-early: cnt (2), list (16, unconditional) ----
    unsigned ec0 = cnt[tile0];
    unsigned ec1 = cnt[tile0 + 1];
    int pk0[PF], pk1[PF];
#pragma unroll
    for (int i = 0; i < PF; ++i) {
        pk0[i] = list[(long)tile0 * CAP + i];
        pk1[i] = list[(long)(tile0 + 1) * CAP + i];
    }

    // ---- idx fill for this block's 256 rows (independent; hides latency) ----
    {
        int j = blockIdx.x * 256 + tid;         // [0, EF)
        int g = j >> 12;
        int rem = j & 4095;
        out[j]      = (float)((g << 6) + (rem >> 6));
        out[EF + j] = (float)((g << 6) + (rem & 63));
    }

    // ---- ea rows: unconditional, index clamped in-bounds ----
    float vpre0[PF], vpre1[PF];
#pragma unroll
    for (int i = 0; i < PF; ++i) {
        unsigned e0 = ((unsigned)pk0[i] >> 5) & (NEDGE - 1);
        unsigned e1 = ((unsigned)pk1[i] >> 5) & (NEDGE - 1);
        vpre0[i] = ea[(long)e0 * DDIM + l];
        vpre1[i] = ea[(long)e1 * DDIM + l];
    }

    unsigned ecc0 = ec0 > CAP ? CAP : ec0;
    unsigned ecc1 = ec1 > CAP ? CAP : ec1;
    unsigned ep0 = ecc0 > PF ? PF : ecc0;
    unsigned ep1 = ecc1 > PF ? PF : ecc1;

    // ---- pv fragments (both tiles) ----
    const float4* bp0 = reinterpret_cast<const float4*>(pv + (j0 + n) * KDIM + kh * 8);
    const float4* bp1 = reinterpret_cast<const float4*>(pv + (j0 + 32 + n) * KDIM + kh * 8);
    float4 ba0 = bp0[0], bb0 = bp0[1], ba1 = bp1[0], bb1 = bp1[1];

    // ---- W fragments (L1-resident) ----
    const float4* wp0 = reinterpret_cast<const float4*>(W + n * KDIM + kh * 8);
    const float4* wp1 = reinterpret_cast<const float4*>(W + (32 + n) * KDIM + kh * 8);
    float4 w0a = wp0[0], w0b = wp0[1], w1a = wp1[0], w1b = wp1[1];
    bf16x8 xa0, xa1;
    xa0[0]=f2bf(w0a.x); xa0[1]=f2bf(w0a.y); xa0[2]=f2bf(w0a.z); xa0[3]=f2bf(w0a.w);
    xa0[4]=f2bf(w0b.x); xa0[5]=f2bf(w0b.y); xa0[6]=f2bf(w0b.z); xa0[7]=f2bf(w0b.w);
    xa1[0]=f2bf(w1a.x); xa1[1]=f2bf(w1a.y); xa1[2]=f2bf(w1a.z); xa1[3]=f2bf(w1a.w);
    xa1[4]=f2bf(w1b.x); xa1[5]=f2bf(w1b.y); xa1[6]=f2bf(w1b.z); xa1[7]=f2bf(w1b.w);

    float* myl = lds[wv];

    // ================= tile 0 =================
    {
        bf16x8 yf;
        yf[0]=f2bf(ba0.x); yf[1]=f2bf(ba0.y); yf[2]=f2bf(ba0.z); yf[3]=f2bf(ba0.w);
        yf[4]=f2bf(bb0.x); yf[5]=f2bf(bb0.y); yf[6]=f2bf(bb0.z); yf[7]=f2bf(bb0.w);
        f32x16 acc0 = {0,0,0,0, 0,0,0,0, 0,0,0,0, 0,0,0,0};
        f32x16 acc1 = {0,0,0,0, 0,0,0,0, 0,0,0,0, 0,0,0,0};
        acc0 = __builtin_amdgcn_mfma_f32_32x32x16_bf16(xa0, yf, acc0, 0, 0, 0);
        acc1 = __builtin_amdgcn_mfma_f32_32x32x16_bf16(xa1, yf, acc1, 0, 0, 0);
#pragma unroll
        for (int q = 0; q < 4; ++q) {
            vfloat4 s0 = {acc0[4*q], acc0[4*q+1], acc0[4*q+2], acc0[4*q+3]};
            vfloat4 s1 = {acc1[4*q], acc1[4*q+1], acc1[4*q+2], acc1[4*q+3]};
            *reinterpret_cast<vfloat4*>(myl + n * LSTR + 8*q + 4*kh)      = s0;
            *reinterpret_cast<vfloat4*>(myl + n * LSTR + 32 + 8*q + 4*kh) = s1;
        }
#pragma unroll
        for (int i = 0; i < PF; ++i)
            if ((unsigned)i < ep0) myl[(pk0[i] & 31) * LSTR + l] += vpre0[i];
        for (unsigned i = PF; i < ecc0; ++i) {     // rare tail
            int packed = list[(long)tile0 * CAP + i];
            myl[(packed & 31) * LSTR + l] += ea[(long)(packed >> 5) * DDIM + l];
        }
#pragma unroll
        for (int i = 0; i < 8; ++i) {
            int row  = 4*i + (l >> 4);
            int colf = (l & 15) * 4;
            vfloat4 v = *reinterpret_cast<const vfloat4*>(myl + row * LSTR + colf);
            *reinterpret_cast<vfloat4*>(outv + (j0 + row) * DDIM + colf) = v;
        }
    }

    // ================= tile 1 =================
    {
        bf16x8 yf;
        yf[0]=f2bf(ba1.x); yf[1]=f2bf(ba1.y); yf[2]=f2bf(ba1.z); yf[3]=f2bf(ba1.w);
        yf[4]=f2bf(bb1.x); yf[5]=f2bf(bb1.y); yf[6]=f2bf(bb1.z); yf[7]=f2bf(bb1.w);
        f32x16 acc0 = {0,0,0,0, 0,0,0,0, 0,0,0,0, 0,0,0,0};
        f32x16 acc1 = {0,0,0,0, 0,0,0,0, 0,0,0,0, 0,0,0,0};
        acc0 = __builtin_amdgcn_mfma_f32_32x32x16_bf16(xa0, yf, acc0, 0, 0, 0);
        acc1 = __builtin_amdgcn_mfma_f32_32x32x16_bf16(xa1, yf, acc1, 0, 0, 0);
#pragma unroll
        for (int q = 0; q < 4; ++q) {
            vfloat4 s0 = {acc0[4*q], acc0[4*q+1], acc0[4*q+2], acc0[4*q+3]};
            vfloat4 s1 = {acc1[4*q], acc1[4*q+1], acc1[4*q+2], acc1[4*q+3]};
            *reinterpret_cast<vfloat4*>(myl + n * LSTR + 8*q + 4*kh)      = s0;
            *reinterpret_cast<vfloat4*>(myl + n * LSTR + 32 + 8*q + 4*kh) = s1;
        }
#pragma unroll
        for (int i = 0; i < PF; ++i)
            if ((unsigned)i < ep1) myl[(pk1[i] & 31) * LSTR + l] += vpre1[i];
        for (unsigned i = PF; i < ecc1; ++i) {     // rare tail
            int packed = list[(long)(tile0 + 1) * CAP + i];
            myl[(packed & 31) * LSTR + l] += ea[(long)(packed >> 5) * DDIM + l];
        }
#pragma unroll
        for (int i = 0; i < 8; ++i) {
            int row  = 4*i + (l >> 4);
            int colf = (l & 15) * 4;
            vfloat4 v = *reinterpret_cast<const vfloat4*>(myl + row * LSTR + colf);
            *reinterpret_cast<vfloat4*>(outv + (j0 + 32 + row) * DDIM + colf) = v;
        }
    }
}

// ---------------------------------------------------------------------------
__global__ __launch_bounds__(256) void ovf_fix(const float* __restrict__ ea,
                                               const int* __restrict__ ei,
                                               const unsigned* __restrict__ ovfc,
                                               const int* __restrict__ ovfl,
                                               float* __restrict__ outv) {
    unsigned nov = *ovfc;
    for (unsigned i = blockIdx.x * 256 + threadIdx.x; i < nov; i += 4 * 256) {
        int e = ovfl[i];
        long slot = edge_slot(ei, e);
        float* dst = outv + slot * DDIM;
        const float* src = ea + (long)e * DDIM;
        for (int j = 0; j < DDIM; ++j) unsafeAtomicAdd(dst + j, src[j]);
    }
}

// ---------------------------------------------------------------------------
// Fallback: proven separate path when ws too small.
// ---------------------------------------------------------------------------
__global__ __launch_bounds__(256) void pv_gemm(const float* __restrict__ pv,
                                               const float* __restrict__ W,
                                               float* __restrict__ outv) {
    __shared__ float lds[4][32 * LSTR];
    int tid = threadIdx.x;
    int wv  = tid >> 6;
    int l   = tid & 63;
    int n   = l & 31;
    int kh  = l >> 5;
    long j0 = ((long)blockIdx.x * 4 + wv) * (32 * TPW);

    const float4* wp0 = reinterpret_cast<const float4*>(W + n * KDIM + kh * 8);
    const float4* wp1 = reinterpret_cast<const float4*>(W + (32 + n) * KDIM + kh * 8);
    float4 w0a = wp0[0], w0b = wp0[1], w1a = wp1[0], w1b = wp1[1];
    bf16x8 xa0, xa1;
    xa0[0]=f2bf(w0a.x); xa0[1]=f2bf(w0a.y); xa0[2]=f2bf(w0a.z); xa0[3]=f2bf(w0a.w);
    xa0[4]=f2bf(w0b.x); xa0[5]=f2bf(w0b.y); xa0[6]=f2bf(w0b.z); xa0[7]=f2bf(w0b.w);
    xa1[0]=f2bf(w1a.x); xa1[1]=f2bf(w1a.y); xa1[2]=f2bf(w1a.z); xa1[3]=f2bf(w1a.w);
    xa1[4]=f2bf(w1b.x); xa1[5]=f2bf(w1b.y); xa1[6]=f2bf(w1b.z); xa1[7]=f2bf(w1b.w);

    float* myl = lds[wv];
#pragma unroll
    for (int t = 0; t < TPW; ++t) {
        long jt = j0 + t * 32;
        const float4* bp = reinterpret_cast<const float4*>(pv + (jt + n) * KDIM + kh * 8);
        float4 ba = bp[0], bb = bp[1];
        bf16x8 yf;
        yf[0]=f2bf(ba.x); yf[1]=f2bf(ba.y); yf[2]=f2bf(ba.z); yf[3]=f2bf(ba.w);
        yf[4]=f2bf(bb.x); yf[5]=f2bf(bb.y); yf[6]=f2bf(bb.z); yf[7]=f2bf(bb.w);

        f32x16 acc0 = {0,0,0,0, 0,0,0,0, 0,0,0,0, 0,0,0,0};
        f32x16 acc1 = {0,0,0,0, 0,0,0,0, 0,0,0,0, 0,0,0,0};
        acc0 = __builtin_amdgcn_mfma_f32_32x32x16_bf16(xa0, yf, acc0, 0, 0, 0);
        acc1 = __builtin_amdgcn_mfma_f32_32x32x16_bf16(xa1, yf, acc1, 0, 0, 0);
#pragma unroll
        for (int q = 0; q < 4; ++q) {
            vfloat4 s0 = {acc0[4*q], acc0[4*q+1], acc0[4*q+2], acc0[4*q+3]};
            vfloat4 s1 = {acc1[4*q], acc1[4*q+1], acc1[4*q+2], acc1[4*q+3]};
            *reinterpret_cast<vfloat4*>(myl + n * LSTR + 8*q + 4*kh)      = s0;
            *reinterpret_cast<vfloat4*>(myl + n * LSTR + 32 + 8*q + 4*kh) = s1;
        }
#pragma unroll
        for (int i = 0; i < 8; ++i) {
            int row  = 4*i + (l >> 4);
            int colf = (l & 15) * 4;
            vfloat4 v = *reinterpret_cast<const vfloat4*>(myl + row * LSTR + colf);
            *reinterpret_cast<vfloat4*>(outv + (jt + row) * DDIM + colf) = v;
        }
    }
}

__global__ __launch_bounds__(256) void fill_idx_plain(float* __restrict__ out) {
    int gid = blockIdx.x * 256 + threadIdx.x;
    int j0 = gid << 2;
    vfloat4 rv, cv;
#pragma unroll
    for (int i = 0; i < 4; ++i) {
        int j = j0 + i;
        int g = j >> 12;
        int rem = j & 4095;
        rv[i] = (float)((g << 6) + (rem >> 6));
        cv[i] = (float)((g << 6) + (rem & 63));
    }
    *reinterpret_cast<vfloat4*>(out + j0)      = rv;
    *reinterpret_cast<vfloat4*>(out + EF + j0) = cv;
}

__global__ __launch_bounds__(256) void scatter_edges(const float* __restrict__ ea,
                                                     const int* __restrict__ ei,
                                                     float* __restrict__ outv) {
    int gid = blockIdx.x * 256 + threadIdx.x;
    int e = gid >> 4;
    int t = gid & 15;
    long slot = edge_slot(ei, e);
    float4 v = *reinterpret_cast<const float4*>(ea + (long)e * DDIM + t * 4);
    float* dst = outv + slot * DDIM + t * 4;
    unsafeAtomicAdd(dst + 0, v.x);
    unsafeAtomicAdd(dst + 1, v.y);
    unsafeAtomicAdd(dst + 2, v.z);
    unsafeAtomicAdd(dst + 3, v.w);
}

extern "C" void kernel_launch(void* const* d_in, const int* in_sizes, int n_in,
                              void* d_out, int out_size, void* d_ws, size_t ws_size,
                              hipStream_t stream) {
    const float* poly_val  = (const float*)d_in[0];
    const float* edge_attr = (const float*)d_in[1];
    const float* W         = (const float*)d_in[2];
    const int*   edge_index = (const int*)d_in[4];

    float* out  = (float*)d_out;
    float* outv = out + 2 * (long)EF;

    if (ws_size >= (size_t)WS_NEED) {
        char* ws = (char*)d_ws;
        unsigned* cnt  = (unsigned*)(ws + WS_CNT_OFF);
        int*      list = (int*)     (ws + WS_LIST_OFF);
        unsigned* ovfc = (unsigned*)(ws + WS_OVFC_OFF);
        int*      ovfl = (int*)     (ws + WS_OVFL_OFF);

        zero_cnt<<<NTILE / 256, 256, 0, stream>>>(cnt, ovfc);
        bin_edges<<<NEDGE / 256, 256, 0, stream>>>(edge_index, cnt, list, ovfc, ovfl);
        pv_fused<<<PVBLK, 256, 0, stream>>>(poly_val, W, edge_attr, cnt, list, out, outv);
        ovf_fix<<<4, 256, 0, stream>>>(edge_attr, edge_index, ovfc, ovfl, outv);
    } else {
        fill_idx_plain<<<EF / 4 / 256, 256, 0, stream>>>(out);
        pv_gemm<<<PVBLK, 256, 0, stream>>>(poly_val, W, outv);
        scatter_edges<<<(NEDGE * 16) / 256, 256, 0, stream>>>(edge_attr, edge_index, outv);
    }
}